// Round 6
// baseline (82.243 us; speedup 1.0000x reference)
//
#include <hip/hip_runtime.h>

// SlotAttention: B=8, L=256, D=256, K=64
// Round-14: L2-BANDWIDTH theory (R2's slope: +160MB duplicated traffic = +5.3us
// ~= 30 TB/s ~= L2 ceiling). Cut L2 traffic ~6x:
//  proj: 8 rows/block, W1 staged in LDS (coalesced, XOR-swizzled slots) ->
//        W1 L2 traffic 256MB -> 32MB. Writes Eq[row][k] + transposed EkT[b][k][j].
//  attn: IPB=8, Ek loads coalesced from EkT (no 4x overfetch), phase-3 D-split
//        (wave = row-quad x d-quarter, lane = one d) -> X[b] read once per block,
//        no cross-wave reduce, no epilogue barrier.
// Math identical: tanh(q+k) = 1 - 2/(Eq*Ek+1); score = -2T; shift-invariant softmax.

#define Bn 8
#define Ln 256
#define Dn 256
#define Kn 64
#define ROWS (Bn*Ln)            // 2048
#define IPB 8                   // rows per block (both kernels)
#define EKT_BASE (ROWS*128)     // float offset of EkT region in ws

// ---------------- Kernel A: projection ----------------
// 256 blocks x 512 thr; thread = (k = tid&63, r = tid>>6). Each thread computes
// qi[row][k] and kj[row][k] (full 256-d dots) from LDS-staged W1 chunks.
__global__ __launch_bounds__(512) void proj_kernel(
    const float* __restrict__ X,    // (2048,256)
    const float* __restrict__ W1,   // (64,512)
    float* __restrict__ QK)         // ws: Eq [2048][128] (c<64 used) + EkT [8][64][256]
{
    __shared__ float Xs[IPB * Dn];  // 8 KB
    __shared__ float Wl[Kn * 128];  // 32 KB, swizzled [k][c4 ^ (k&31)] float4 slots
    const int tid = threadIdx.x;
    const int r0 = blockIdx.x * IPB;

    ((float4*)Xs)[tid] = ((const float4*)(X + r0 * Dn))[tid];  // 8 rows coalesced

    const int k = tid & 63;
    const int r = tid >> 6;          // 0..7
    float accI = 0.f, accJ = 0.f;

    #pragma unroll
    for (int h = 0; h < 2; ++h) {
        #pragma unroll
        for (int ds = 0; ds < 2; ++ds) {
            __syncthreads();         // Xs ready (1st) / Wl consumed (later)
            // stage 32KB chunk: W1[kk][h*256 + ds*128 + 0..127], coalesced
            #pragma unroll
            for (int t = 0; t < 4; ++t) {
                int f  = tid + t * 512;
                int kk = f >> 5, c4 = f & 31;
                float4 w = *(const float4*)(W1 + kk * (2 * Dn) + h * Dn + ds * 128 + c4 * 4);
                ((float4*)Wl)[kk * 32 + (c4 ^ (kk & 31))] = w;   // swizzled slot
            }
            __syncthreads();
            float a = 0.f;
            const float4* xrow = (const float4*)(Xs + r * Dn + ds * 128);
            #pragma unroll
            for (int c4 = 0; c4 < 32; ++c4) {
                float4 w = ((const float4*)Wl)[k * 32 + (c4 ^ (k & 31))]; // even banks
                float4 x = xrow[c4];                                     // uniform bcast
                a = fmaf(w.x, x.x, a); a = fmaf(w.y, x.y, a);
                a = fmaf(w.z, x.z, a); a = fmaf(w.w, x.w, a);
            }
            if (h == 0) accI += a; else accJ += a;
        }
    }

    const int row = r0 + r;
    QK[row * 128 + k] = __expf(2.0f * accI);                 // Eq, coalesced
    const int bb = row >> 8, jj = row & 255;
    QK[EKT_BASE + bb * (Kn * Ln) + k * Ln + jj] = __expf(2.0f * accJ);  // EkT
}

// ---------------- Kernel B: scores + softmax + context ----------------
// 256 blocks x 512 thr (8 waves). Phase1 thread = (j = tid&255, kh = tid>>8).
// Phase2 wave wv = row i. Phase3 wave = (rq = wv>>2, dh = wv&3), lane = one d.
__global__ __launch_bounds__(512) void attn_kernel(
    const float* __restrict__ X,    // (2048,256)
    const float* __restrict__ QK,   // ws (exp'd)
    const float* __restrict__ W2,   // (64,)
    float* __restrict__ out)        // (2048,512)
{
    __shared__ float eq_s[IPB * Kn];     // [i][k]  2 KB
    __shared__ float w2_s[Kn];           // 256 B
    __shared__ float Sp[2 * IPB * Ln];   // [kh][i][j] partial T, 16 KB
    __shared__ float S8[Ln * IPB];       // [j][i] attn weights, 8 KB

    const int tid = threadIdx.x;
    const int b  = blockIdx.x >> 5;          // 32 blocks per batch
    const int i0 = (blockIdx.x & 31) * IPB;
    const int j  = tid & 255;
    const int kh = tid >> 8;

    if (tid < Kn) w2_s[tid] = W2[tid];
    eq_s[tid] = QK[(b * Ln + i0 + (tid >> 6)) * 128 + (tid & 63)];  // [i][k] coalesced

    // Ek: 32 coalesced scalar loads from EkT[b][k][j] (lanes j consecutive)
    float ekr[32];
    {
        const float* ekt = QK + EKT_BASE + b * (Kn * Ln) + (kh * 32) * Ln + j;
        #pragma unroll
        for (int kk = 0; kk < 32; ++kk) ekr[kk] = ekt[kk * Ln];
    }
    __syncthreads();

    // Phase 1: partial T_i (8 rows) over this thread's 32 k's
    {
        float s[IPB] = {0, 0, 0, 0, 0, 0, 0, 0};
        const float4* w4 = ((const float4*)w2_s) + kh * 8;
        #pragma unroll
        for (int k4 = 0; k4 < 8; ++k4) {
            float4 w = w4[k4];                       // uniform bcast
            float4 q[IPB];
            #pragma unroll
            for (int i = 0; i < IPB; ++i)
                q[i] = ((const float4*)(eq_s + i * Kn))[kh * 8 + k4];  // uniform bcast
            #pragma unroll
            for (int c = 0; c < 4; ++c) {
                float ek = ekr[k4 * 4 + c];
                float wk = (c == 0) ? w.x : (c == 1) ? w.y : (c == 2) ? w.z : w.w;
                #pragma unroll
                for (int i = 0; i < IPB; ++i) {
                    float e = (c == 0) ? q[i].x : (c == 1) ? q[i].y
                            : (c == 2) ? q[i].z : q[i].w;
                    s[i] = fmaf(wk, __builtin_amdgcn_rcpf(fmaf(e, ek, 1.0f)), s[i]);
                }
            }
        }
        #pragma unroll
        for (int i = 0; i < IPB; ++i)
            Sp[(kh * IPB + i) * Ln + j] = s[i];      // lanes j consecutive, no conflict
    }
    __syncthreads();

    // Phase 2: softmax over j of (-2T); wave wv owns row i = wv (all 8 waves busy)
    {
        const int wv = tid >> 6, lane = tid & 63;
        const float* p0 = Sp + wv * Ln;              // kh=0 partials
        const float* p1 = Sp + (IPB + wv) * Ln;      // kh=1 partials
        float e0 = __expf(-2.0f * (p0[lane      ] + p1[lane      ]));
        float e1 = __expf(-2.0f * (p0[lane +  64] + p1[lane +  64]));
        float e2 = __expf(-2.0f * (p0[lane + 128] + p1[lane + 128]));
        float e3 = __expf(-2.0f * (p0[lane + 192] + p1[lane + 192]));
        float sum = (e0 + e1) + (e2 + e3);
        #pragma unroll
        for (int off = 32; off > 0; off >>= 1)
            sum += __shfl_xor(sum, off);
        float inv = 1.0f / sum;
        S8[(lane      ) * IPB + wv] = e0 * inv;      // S8[j][i]
        S8[(lane +  64) * IPB + wv] = e1 * inv;
        S8[(lane + 128) * IPB + wv] = e2 * inv;
        S8[(lane + 192) * IPB + wv] = e3 * inv;
    }
    __syncthreads();

    // inputs -> out copy (no barrier after; overlaps phase 3)
    {
        const int i = tid >> 6, q = tid & 63;
        const int row = b * Ln + i0 + i;
        ((float4*)(out + row * 2 * Dn))[q] = ((const float4*)(X + row * Dn))[q];
    }

    // Phase 3: D-split context. wave = (rq, dh); lane owns d = dh*64 + lane.
    // X[b] is read exactly once per block (rq-pairs share lines via L1).
    {
        const int wv = tid >> 6, lane = tid & 63;
        const int rq = wv >> 2, dh = wv & 3;
        const int d  = dh * 64 + lane;
        const float* Xb = X + b * Ln * Dn + d;
        float a0 = 0.f, a1 = 0.f, a2 = 0.f, a3 = 0.f;
        #pragma unroll 8
        for (int jj = 0; jj < Ln; ++jj) {
            float4 at = *(const float4*)(S8 + jj * IPB + rq * 4);  // uniform bcast b128
            float xv = Xb[jj * Dn];                                // coalesced 256B
            a0 = fmaf(at.x, xv, a0);
            a1 = fmaf(at.y, xv, a1);
            a2 = fmaf(at.z, xv, a2);
            a3 = fmaf(at.w, xv, a3);
        }
        const int row0 = b * Ln + i0 + rq * 4;
        out[(row0 + 0) * 2 * Dn + Dn + d] = a0;      // coalesced 256B stores
        out[(row0 + 1) * 2 * Dn + Dn + d] = a1;
        out[(row0 + 2) * 2 * Dn + Dn + d] = a2;
        out[(row0 + 3) * 2 * Dn + Dn + d] = a3;
    }
}

extern "C" void kernel_launch(void* const* d_in, const int* in_sizes, int n_in,
                              void* d_out, int out_size, void* d_ws, size_t ws_size,
                              hipStream_t stream) {
    const float* X  = (const float*)d_in[0];   // (8,256,256)
    const float* W1 = (const float*)d_in[1];   // (64,512)
    const float* W2 = (const float*)d_in[2];   // (1,64)
    float* out = (float*)d_out;                // (8,256,512)
    float* QK  = (float*)d_ws;                 // 1.5 MB scratch (Eq + EkT)

    proj_kernel<<<ROWS / IPB, 512, 0, stream>>>(X, W1, QK);
    attn_kernel<<<ROWS / IPB, 512, 0, stream>>>(X, QK, W2, out);
}

// Round 7
// 79.282 us; speedup vs baseline: 1.0373x; 1.0373x over previous
//
#include <hip/hip_runtime.h>

// SlotAttention: B=8, L=256, D=256, K=64
// Round-15: reinstate the measured-best variant (R3 / round-11 structure, 79.0us).
// Session conclusion from 6 controlled perturbations:
//   occupancy x2 (R3): -0.7us | reg-pinning (R5): +1.3us | L2 traffic /6 (R6): +3.2us
// -> kernel-side contribution is ~4-8us; dur_us is dominated by a fixed harness
//    window (256MB ws poison fill = 40.3us @ 83% HBM in every profile's top-5,
//    plus launch/sync overhead). R3 is the empirical minimum; later "fixes"
//    were neutral-to-negative, so this is the keeper.
// Math: tanh(q+k) = 1 - 2/(Eq*Ek+1); score = -2T (shift-invariant softmax,
// no max-subtract needed since |2T| <= ~13).

#define Bn 8
#define Ln 256
#define Dn 256
#define Kn 64
#define ROWS (Bn*Ln)       // 2048
#define IPB 4              // query rows per attn block

// ---------------- Kernel A: projection -> exp form (256 thr, d-split) ----------------
// QK[row][c]: c<64 -> Eq = e^{2*qi[k=c]}, c>=64 -> Ek = e^{2*kj[k=c-64]}
__global__ __launch_bounds__(256) void proj_kernel(
    const float* __restrict__ X,    // (2048,256)
    const float* __restrict__ W1,   // (64,512)
    float* __restrict__ QK)         // (2048,128)
{
    __shared__ float Xs[4 * Dn];    // 4 rows, 4 KB
    __shared__ float pr[128 * 4];   // 2 KB partial dots (d-half 1)
    const int tid = threadIdx.x;
    const int r0 = blockIdx.x * 4;

    ((float4*)Xs)[tid] = ((const float4*)(X + r0 * Dn))[tid];   // 4 rows coalesced
    __syncthreads();

    const int c    = tid & 127;     // output col: c<64 Eq(k=c), c>=64 Ek(k=c-64)
    const int dh   = tid >> 7;      // d-half: 0 -> d[0:128), 1 -> d[128:256)
    const int k    = c & 63;
    const int half = c >> 6;
    const float4* Wrow = (const float4*)(W1 + k * (2 * Dn) + half * Dn + dh * (Dn / 2));
    const float4* x0p = (const float4*)(Xs + 0 * Dn + dh * (Dn / 2));
    const float4* x1p = (const float4*)(Xs + 1 * Dn + dh * (Dn / 2));
    const float4* x2p = (const float4*)(Xs + 2 * Dn + dh * (Dn / 2));
    const float4* x3p = (const float4*)(Xs + 3 * Dn + dh * (Dn / 2));
    float a0 = 0.f, a1 = 0.f, a2 = 0.f, a3 = 0.f;
    #pragma unroll 8
    for (int d4 = 0; d4 < 32; ++d4) {
        float4 w  = Wrow[d4];
        float4 x0 = x0p[d4], x1 = x1p[d4], x2 = x2p[d4], x3 = x3p[d4];  // LDS broadcast
        a0 = fmaf(w.x, x0.x, a0); a0 = fmaf(w.y, x0.y, a0);
        a0 = fmaf(w.z, x0.z, a0); a0 = fmaf(w.w, x0.w, a0);
        a1 = fmaf(w.x, x1.x, a1); a1 = fmaf(w.y, x1.y, a1);
        a1 = fmaf(w.z, x1.z, a1); a1 = fmaf(w.w, x1.w, a1);
        a2 = fmaf(w.x, x2.x, a2); a2 = fmaf(w.y, x2.y, a2);
        a2 = fmaf(w.z, x2.z, a2); a2 = fmaf(w.w, x2.w, a2);
        a3 = fmaf(w.x, x3.x, a3); a3 = fmaf(w.y, x3.y, a3);
        a3 = fmaf(w.z, x3.z, a3); a3 = fmaf(w.w, x3.w, a3);
    }
    if (dh) ((float4*)pr)[c] = make_float4(a0, a1, a2, a3);
    __syncthreads();
    if (!dh) {
        float4 p = ((const float4*)pr)[c];
        QK[(r0 + 0) * 128 + c] = __expf(2.0f * (a0 + p.x));
        QK[(r0 + 1) * 128 + c] = __expf(2.0f * (a1 + p.y));
        QK[(r0 + 2) * 128 + c] = __expf(2.0f * (a2 + p.z));
        QK[(r0 + 3) * 128 + c] = __expf(2.0f * (a3 + p.w));
    }
}

// ---------------- Kernel B: scores + softmax + context (IPB=4, 512 thr) ----------------
// grid = 512 blocks, 512 threads (8 waves). Thread = (j = tid&255, kh = tid>>8).
__global__ __launch_bounds__(512, 4) void attn_kernel(
    const float* __restrict__ X,    // (2048,256)
    const float* __restrict__ QK,   // (2048,128) exp'd
    const float* __restrict__ W2,   // (64,)
    float* __restrict__ out)        // (2048,512)
{
    __shared__ float eq_s[IPB * Kn];        // 1 KB
    __shared__ float w2_s[Kn];              // 256 B
    __shared__ float Sp[2 * IPB * Ln];      // [kh][i][j] partial T, 8 KB
    __shared__ float4 S4[Ln];               // final attn per j (components = i), 4 KB
    __shared__ float4 red[8 * IPB * 64];    // [wv][i][dquad], 32 KB

    const int tid = threadIdx.x;
    const int b  = blockIdx.x >> 6;             // 64 blocks per batch
    const int i0 = (blockIdx.x & 63) * IPB;
    const int j  = tid & 255;                   // key row owned
    const int kh = tid >> 8;                    // k-half: 0 -> k[0:32), 1 -> k[32:64)

    if (tid < Kn) w2_s[tid] = W2[tid];
    if (tid >= 256) {                           // waves 4-7 load Eq (256 values)
        int t = tid - 256;
        int ii = t >> 6, kk = t & 63;
        eq_s[ii * Kn + kk] = QK[(b * Ln + i0 + ii) * 128 + kk];
    }

    // prefetch this thread's Ek half-row (32 floats) to registers
    float ekr[32];
    {
        const float4* kj4 = (const float4*)(QK + (b * Ln + j) * 128 + 64 + kh * 32);
        #pragma unroll
        for (int q = 0; q < 8; ++q) {
            float4 v = kj4[q];
            ekr[q * 4 + 0] = v.x; ekr[q * 4 + 1] = v.y;
            ekr[q * 4 + 2] = v.z; ekr[q * 4 + 3] = v.w;
        }
    }
    __syncthreads();

    // Phase 1: partial T_i over this thread's 32 k's.
    {
        float s0 = 0.f, s1 = 0.f, s2 = 0.f, s3 = 0.f;
        const float4* w4  = ((const float4*)w2_s) + kh * 8;
        const float4* q4a = ((const float4*)(eq_s          )) + kh * 8;
        const float4* q4b = ((const float4*)(eq_s +     Kn )) + kh * 8;
        const float4* q4c = ((const float4*)(eq_s + 2 * Kn )) + kh * 8;
        const float4* q4d = ((const float4*)(eq_s + 3 * Kn )) + kh * 8;
        #pragma unroll
        for (int k4 = 0; k4 < 8; ++k4) {
            float4 w  = w4[k4];                 // uniform LDS broadcast
            float4 q0 = q4a[k4], q1 = q4b[k4], q2 = q4c[k4], q3 = q4d[k4];
            #pragma unroll
            for (int c = 0; c < 4; ++c) {
                float ek = ekr[k4 * 4 + c];
                float wk = (c == 0) ? w.x : (c == 1) ? w.y : (c == 2) ? w.z : w.w;
                float e0 = (c == 0) ? q0.x : (c == 1) ? q0.y : (c == 2) ? q0.z : q0.w;
                float e1 = (c == 0) ? q1.x : (c == 1) ? q1.y : (c == 2) ? q1.z : q1.w;
                float e2 = (c == 0) ? q2.x : (c == 1) ? q2.y : (c == 2) ? q2.z : q2.w;
                float e3 = (c == 0) ? q3.x : (c == 1) ? q3.y : (c == 2) ? q3.z : q3.w;
                s0 = fmaf(wk, __builtin_amdgcn_rcpf(fmaf(e0, ek, 1.0f)), s0);
                s1 = fmaf(wk, __builtin_amdgcn_rcpf(fmaf(e1, ek, 1.0f)), s1);
                s2 = fmaf(wk, __builtin_amdgcn_rcpf(fmaf(e2, ek, 1.0f)), s2);
                s3 = fmaf(wk, __builtin_amdgcn_rcpf(fmaf(e3, ek, 1.0f)), s3);
            }
        }
        // transposed store [kh][i][j]: lanes stride 4 B -> conflict-free
        Sp[(kh * IPB + 0) * Ln + j] = s0;
        Sp[(kh * IPB + 1) * Ln + j] = s1;
        Sp[(kh * IPB + 2) * Ln + j] = s2;
        Sp[(kh * IPB + 3) * Ln + j] = s3;
    }
    __syncthreads();

    // Phase 2 (waves 0-3): softmax over j of (-2T), row i = wv.
    // Waves 4-7 concurrently: inputs -> out copy.
    {
        const int wv = tid >> 6, lane = tid & 63;
        if (wv < IPB) {
            const float* p0 = Sp + wv * Ln;             // kh=0 partials, row wv
            const float* p1 = Sp + (IPB + wv) * Ln;     // kh=1 partials
            float T0 = p0[lane      ] + p1[lane      ];
            float T1 = p0[lane +  64] + p1[lane +  64];
            float T2 = p0[lane + 128] + p1[lane + 128];
            float T3 = p0[lane + 192] + p1[lane + 192];
            float e0 = __expf(-2.0f * T0);
            float e1 = __expf(-2.0f * T1);
            float e2 = __expf(-2.0f * T2);
            float e3 = __expf(-2.0f * T3);
            float sum = (e0 + e1) + (e2 + e3);
            #pragma unroll
            for (int off = 32; off > 0; off >>= 1)
                sum += __shfl_xor(sum, off);
            float inv = 1.0f / sum;
            ((float*)S4)[(lane      ) * 4 + wv] = e0 * inv;
            ((float*)S4)[(lane +  64) * 4 + wv] = e1 * inv;
            ((float*)S4)[(lane + 128) * 4 + wv] = e2 * inv;
            ((float*)S4)[(lane + 192) * 4 + wv] = e3 * inv;
        } else {
            int t = tid - 256;
            int ii = t >> 6, q = t & 63;
            const int row = b * Ln + i0 + ii;
            ((float4*)(out + row * 2 * Dn))[q] = ((const float4*)(X + row * Dn))[q];
        }
    }
    __syncthreads();

    // Phase 3: context, j split across 8 waves (32 j each)
    {
        const int wv = tid >> 6, lane = tid & 63;
        float4 acc0 = {0,0,0,0}, acc1 = {0,0,0,0}, acc2 = {0,0,0,0}, acc3 = {0,0,0,0};
        const float4* Xb4 = (const float4*)(X + b * Ln * Dn);
        const int jbase = wv * 32;
        #pragma unroll 8
        for (int jj = 0; jj < 32; ++jj) {
            int jr = jbase + jj;
            float4 at = S4[jr];                // uniform broadcast b128
            float4 x  = Xb4[jr * 64 + lane];   // coalesced 1 KB/wave
            acc0.x = fmaf(at.x, x.x, acc0.x); acc0.y = fmaf(at.x, x.y, acc0.y);
            acc0.z = fmaf(at.x, x.z, acc0.z); acc0.w = fmaf(at.x, x.w, acc0.w);
            acc1.x = fmaf(at.y, x.x, acc1.x); acc1.y = fmaf(at.y, x.y, acc1.y);
            acc1.z = fmaf(at.y, x.z, acc1.z); acc1.w = fmaf(at.y, x.w, acc1.w);
            acc2.x = fmaf(at.z, x.x, acc2.x); acc2.y = fmaf(at.z, x.y, acc2.y);
            acc2.z = fmaf(at.z, x.z, acc2.z); acc2.w = fmaf(at.z, x.w, acc2.w);
            acc3.x = fmaf(at.w, x.x, acc3.x); acc3.y = fmaf(at.w, x.y, acc3.y);
            acc3.z = fmaf(at.w, x.z, acc3.z); acc3.w = fmaf(at.w, x.w, acc3.w);
        }
        red[(wv * IPB + 0) * 64 + lane] = acc0;
        red[(wv * IPB + 1) * 64 + lane] = acc1;
        red[(wv * IPB + 2) * 64 + lane] = acc2;
        red[(wv * IPB + 3) * 64 + lane] = acc3;
    }
    __syncthreads();

    // Epilogue (waves 0-3): cross-wave reduce of 8 partials + context store
    if (tid < 256) {
        const int i = tid >> 6, q = tid & 63;
        float4 c = {0, 0, 0, 0};
        #pragma unroll
        for (int w = 0; w < 8; ++w) {
            float4 p = red[(w * IPB + i) * 64 + q];
            c.x += p.x; c.y += p.y; c.z += p.z; c.w += p.w;
        }
        const int row = b * Ln + i0 + i;
        ((float4*)(out + row * 2 * Dn + Dn))[q] = c;   // context half
    }
}

extern "C" void kernel_launch(void* const* d_in, const int* in_sizes, int n_in,
                              void* d_out, int out_size, void* d_ws, size_t ws_size,
                              hipStream_t stream) {
    const float* X  = (const float*)d_in[0];   // (8,256,256)
    const float* W1 = (const float*)d_in[1];   // (64,512)
    const float* W2 = (const float*)d_in[2];   // (1,64)
    float* out = (float*)d_out;                // (8,256,512)
    float* QK  = (float*)d_ws;                 // (2048,128) = 1 MB scratch

    proj_kernel<<<ROWS / 4, 256, 0, stream>>>(X, W1, QK);
    attn_kernel<<<ROWS / IPB, 512, 0, stream>>>(X, QK, W2, out);
}